// Round 1
// baseline (2546.463 us; speedup 1.0000x reference)
//
#include <hip/hip_runtime.h>
#include <cstdint>
#include <cstddef>

// ---------------------------------------------------------------------------
// dims
#define BB 16
#define TT 200
#define SS 100
#define EE 256
#define HH 8
#define LL 2
#define FF 1024
#define VV 50000
#define DTXT 768
#define DIMG 512
#define GHH 64
#define MROWS (BB * TT)   // 3200
#define MENC  (BB * SS)   // 1600

using bf16x8 = __attribute__((ext_vector_type(8))) short;   // 8 bf16
using f32x4  = __attribute__((ext_vector_type(4))) float;

// fp32 -> bf16 RTNE (bit trick; inputs are sane, NaN not a concern)
__device__ __forceinline__ short f2bf(float f) {
    unsigned u = __float_as_uint(f);
    u += 0x7fffu + ((u >> 16) & 1u);
    return (short)(u >> 16);
}

// ---------------------------------------------------------------------------
// transpose fp32 [K,N] -> bf16 [N,K]
__global__ __launch_bounds__(256)
void k_transpose_bf16(const float* __restrict__ in, short* __restrict__ out, int K, int N) {
    __shared__ float tile[32][33];
    int n0 = blockIdx.x * 32, k0 = blockIdx.y * 32;
    for (int i = threadIdx.y; i < 32; i += 8) {
        int k = k0 + i, n = n0 + threadIdx.x;
        tile[i][threadIdx.x] = (k < K && n < N) ? in[(size_t)k * N + n] : 0.f;
    }
    __syncthreads();
    for (int i = threadIdx.y; i < 32; i += 8) {
        int n = n0 + i, k = k0 + threadIdx.x;
        if (n < N && k < K) out[(size_t)n * K + k] = f2bf(tile[threadIdx.x][i]);
    }
}

// ---------------------------------------------------------------------------
// Generic bf16 MFMA GEMM:  C[M,N] = act( A[M,K](f32, optional row-gather) @ Bt[N,K](bf16)^T + bias )
// block = 256 (4 waves), block tile 128x128, wave tile 64x64 = 4x4 MFMA tiles.
// A fragment: lane holds A[m = lane&15][k = (lane>>4)*8 + j]
// B fragment: lane holds B[k = (lane>>4)*8 + j][n = lane&15]  (from Bt row n)
// D: lane reg i -> row=(lane>>4)*4+i, col=lane&15   [verified layout per guide m89/m91]
__global__ __launch_bounds__(256)
void k_gemm_bf16(const float* __restrict__ A, int lda, const int* __restrict__ aidx,
                 const short* __restrict__ Bt, const float* __restrict__ bias,
                 float* __restrict__ C, int ldc, int M, int N, int K, int dorelu) {
    int tid  = threadIdx.x;
    int wave = tid >> 6, lane = tid & 63;
    int lr = lane & 15, lq = lane >> 4;
    int m_base = blockIdx.y * 128 + (wave >> 1) * 64;
    int n_base = blockIdx.x * 128 + (wave & 1) * 64;

    const float* arow[4];
    const short* brow[4];
#pragma unroll
    for (int mt = 0; mt < 4; ++mt) {
        int m = m_base + mt * 16 + lr;
        if (m >= M) m = M - 1;
        int r = aidx ? aidx[m] : m;
        arow[mt] = A + (size_t)r * lda + lq * 8;
    }
#pragma unroll
    for (int nt = 0; nt < 4; ++nt) {
        int n = n_base + nt * 16 + lr;
        if (n >= N) n = N - 1;
        brow[nt] = Bt + (size_t)n * K + lq * 8;
    }

    f32x4 acc[4][4];
#pragma unroll
    for (int a = 0; a < 4; ++a)
#pragma unroll
        for (int b = 0; b < 4; ++b)
#pragma unroll
            for (int i = 0; i < 4; ++i) acc[a][b][i] = 0.f;

    for (int k0 = 0; k0 < K; k0 += 32) {
        bf16x8 af[4], bfr[4];
#pragma unroll
        for (int mt = 0; mt < 4; ++mt) {
            const float4* p = (const float4*)(arow[mt] + k0);
            float4 u = p[0], v = p[1];
            bf16x8 t;
            t[0] = f2bf(u.x); t[1] = f2bf(u.y); t[2] = f2bf(u.z); t[3] = f2bf(u.w);
            t[4] = f2bf(v.x); t[5] = f2bf(v.y); t[6] = f2bf(v.z); t[7] = f2bf(v.w);
            af[mt] = t;
        }
#pragma unroll
        for (int nt = 0; nt < 4; ++nt)
            bfr[nt] = *(const bf16x8*)(brow[nt] + k0);
#pragma unroll
        for (int mt = 0; mt < 4; ++mt)
#pragma unroll
            for (int nt = 0; nt < 4; ++nt)
                acc[mt][nt] = __builtin_amdgcn_mfma_f32_16x16x32_bf16(af[mt], bfr[nt], acc[mt][nt], 0, 0, 0);
    }

#pragma unroll
    for (int mt = 0; mt < 4; ++mt)
#pragma unroll
        for (int nt = 0; nt < 4; ++nt) {
            int col = n_base + nt * 16 + lr;
            if (col >= N) continue;
            float bv = bias ? bias[col] : 0.f;
#pragma unroll
            for (int i = 0; i < 4; ++i) {
                int row = m_base + mt * 16 + lq * 4 + i;
                if (row >= M) continue;
                float v = acc[mt][nt][i] + bv;
                if (dorelu) v = fmaxf(v, 0.f);
                C[(size_t)row * ldc + col] = v;
            }
        }
}

// ---------------------------------------------------------------------------
// attention: one block per (b,h), 256 threads, thread t handles query row t.
// K/V staged in LDS. MODE: 0=none, 1=causal, 2=pad mask (+NEG on masked s).
template <int MODE>
__global__ __launch_bounds__(256)
void k_attn(const float* __restrict__ q, int qld,
            const float* __restrict__ k, const float* __restrict__ v, int kvld,
            const int* __restrict__ mask,
            float* __restrict__ out, int T, int Tk) {
    int b = blockIdx.z, h = blockIdx.y;
    int t = threadIdx.x;
    __shared__ float kl[TT][32];
    __shared__ float vl[TT][32];
    for (int idx = threadIdx.x; idx < Tk * 32; idx += 256) {
        int s = idx >> 5, i = idx & 31;
        kl[s][i] = k[((size_t)b * Tk + s) * kvld + h * 32 + i];
        vl[s][i] = v[((size_t)b * Tk + s) * kvld + h * 32 + i];
    }
    __syncthreads();
    if (t >= T) return;

    float qv[32];
    const float* qp = q + ((size_t)b * T + t) * qld + h * 32;
#pragma unroll
    for (int i = 0; i < 32; ++i) qv[i] = qp[i];

    float m = -INFINITY, l = 0.f, ctx[32];
#pragma unroll
    for (int i = 0; i < 32; ++i) ctx[i] = 0.f;

    int send = (MODE == 1) ? (t + 1) : Tk;
    for (int s = 0; s < send; ++s) {
        float d = 0.f;
#pragma unroll
        for (int i = 0; i < 32; ++i) d += qv[i] * kl[s][i];
        d *= 0.17677669529663687f;  // 1/sqrt(32)
        if (MODE == 2) { if (mask[b * Tk + s]) d += -1e9f; }
        if (d > m) {
            float f = __expf(m - d);
            l *= f;
#pragma unroll
            for (int i = 0; i < 32; ++i) ctx[i] *= f;
            m = d;
        }
        float p = __expf(d - m);
        l += p;
#pragma unroll
        for (int i = 0; i < 32; ++i) ctx[i] += p * vl[s][i];
    }
    float inv = 1.f / l;
    float* op = out + ((size_t)b * T + t) * EE + h * 32;
#pragma unroll
    for (int i = 0; i < 32; ++i) op[i] = ctx[i] * inv;
}

// ---------------------------------------------------------------------------
// LayerNorm(res = a + b) with gain/beta, E=256, one block per row, in-place safe.
__global__ __launch_bounds__(256)
void k_ln_res(const float* __restrict__ a, const float* __restrict__ bres,
              const float* __restrict__ gain, const float* __restrict__ beta,
              float* __restrict__ out) {
    int row = blockIdx.x, i = threadIdx.x;
    __shared__ float red[256];
    float x = a[(size_t)row * EE + i] + bres[(size_t)row * EE + i];
    red[i] = x;
    __syncthreads();
    for (int s = 128; s > 0; s >>= 1) { if (i < s) red[i] += red[i + s]; __syncthreads(); }
    float mu = red[0] * (1.f / EE);
    __syncthreads();
    float d = x - mu;
    red[i] = d * d;
    __syncthreads();
    for (int s = 128; s > 0; s >>= 1) { if (i < s) red[i] += red[i + s]; __syncthreads(); }
    float var = red[0] * (1.f / EE);
    float r = rsqrtf(var + 1e-5f);
    out[(size_t)row * EE + i] = d * r * gain[i] + beta[i];
}

// ---------------------------------------------------------------------------
// gate: softmax(relu(x@g_w1+g_b1)@g_w2+g_b2) per row. block=64 per row.
__global__ __launch_bounds__(64)
void k_gate(const float* __restrict__ x, const float* __restrict__ w1, const float* __restrict__ b1,
            const float* __restrict__ w2, const float* __restrict__ b2, float* __restrict__ gate) {
    int row = blockIdx.x, j = threadIdx.x;
    __shared__ float xr[EE];
    __shared__ float hr[GHH];
    for (int i = j; i < EE; i += 64) xr[i] = x[(size_t)row * EE + i];
    __syncthreads();
    float acc = b1[j];
    for (int i = 0; i < EE; ++i) acc += xr[i] * w1[i * GHH + j];
    hr[j] = fmaxf(acc, 0.f);
    __syncthreads();
    if (j == 0) {
        float g[3];
        for (int c = 0; c < 3; ++c) {
            float a = b2[c];
            for (int kk = 0; kk < GHH; ++kk) a += hr[kk] * w2[kk * 3 + c];
            g[c] = a;
        }
        float mx = fmaxf(g[0], fmaxf(g[1], g[2]));
        float e0 = __expf(g[0] - mx), e1 = __expf(g[1] - mx), e2 = __expf(g[2] - mx);
        float inv = 1.f / (e0 + e1 + e2);
        gate[(size_t)row * 3 + 0] = e0 * inv;
        gate[(size_t)row * 3 + 1] = e1 * inv;
        gate[(size_t)row * 3 + 2] = e2 * inv;
    }
}

// ---------------------------------------------------------------------------
__global__ __launch_bounds__(256)
void k_embed(const int* __restrict__ ids, const float* __restrict__ item,
             const float* __restrict__ pos, float* __restrict__ out) {
    int idx = blockIdx.x * 256 + threadIdx.x;
    if (idx >= MROWS * EE) return;
    int bt = idx >> 8, e = idx & 255;
    int t = bt % TT;
    out[idx] = item[(size_t)ids[bt] * EE + e] * 16.f + pos[t * EE + e];
}

__global__ __launch_bounds__(256)
void k_combine(const float* __restrict__ g, const float* __restrict__ e0,
               const float* __restrict__ e1, const float* __restrict__ e2,
               float* __restrict__ out) {
    int idx = blockIdx.x * 256 + threadIdx.x;
    if (idx >= MROWS * EE) return;
    int row = idx >> 8;
    out[idx] = g[(size_t)row * 3] * e0[idx] + g[(size_t)row * 3 + 1] * e1[idx] + g[(size_t)row * 3 + 2] * e2[idx];
}

// ---------------------------------------------------------------------------
extern "C" void kernel_launch(void* const* d_in, const int* in_sizes, int n_in,
                              void* d_out, int out_size, void* d_ws, size_t ws_size,
                              hipStream_t stream) {
    (void)in_sizes; (void)n_in; (void)out_size; (void)ws_size;

    const int*   ids      = (const int*)d_in[0];
    const float* enc      = (const float*)d_in[1];
    const int*   mask     = (const int*)d_in[2];
    const float* item_emb = (const float*)d_in[3];
    const float* pos_emb  = (const float*)d_in[4];
    const float* sa_qkv_w = (const float*)d_in[5];
    const float* sa_qkv_b = (const float*)d_in[6];
    const float* sa_out_w = (const float*)d_in[7];
    const float* sa_out_b = (const float*)d_in[8];
    const float* ca_qkv_w = (const float*)d_in[9];
    const float* ca_qkv_b = (const float*)d_in[10];
    const float* ca_out_w = (const float*)d_in[11];
    const float* ca_out_b = (const float*)d_in[12];
    const float* n1_s = (const float*)d_in[13];
    const float* n1_b = (const float*)d_in[14];
    const float* n2_s = (const float*)d_in[15];
    const float* n2_b = (const float*)d_in[16];
    const float* n3_s = (const float*)d_in[17];
    const float* n3_b = (const float*)d_in[18];
    const float* ffn_w1 = (const float*)d_in[19];
    const float* ffn_b1 = (const float*)d_in[20];
    const float* ffn_w2 = (const float*)d_in[21];
    const float* ffn_b2 = (const float*)d_in[22];
    const float* g_w1 = (const float*)d_in[23];
    const float* g_b1 = (const float*)d_in[24];
    const float* g_w2 = (const float*)d_in[25];
    const float* g_b2 = (const float*)d_in[26];
    const float* be_w = (const float*)d_in[27];
    const float* be_b = (const float*)d_in[28];
    const float* text_mat = (const float*)d_in[29];
    const float* tp_w = (const float*)d_in[30];
    const float* tp_b = (const float*)d_in[31];
    const float* ct_qkv_w = (const float*)d_in[32];
    const float* ct_qkv_b = (const float*)d_in[33];
    const float* ct_out_w = (const float*)d_in[34];
    const float* ct_out_b = (const float*)d_in[35];
    const float* ce_w1 = (const float*)d_in[36];
    const float* ce_b1 = (const float*)d_in[37];
    const float* ce_w2 = (const float*)d_in[38];
    const float* ce_b2 = (const float*)d_in[39];
    const float* img_mat = (const float*)d_in[40];
    const float* ip_w = (const float*)d_in[41];
    const float* ip_b = (const float*)d_in[42];
    const float* im_qkv_w = (const float*)d_in[43];
    const float* im_qkv_b = (const float*)d_in[44];
    const float* im_out_w = (const float*)d_in[45];
    const float* im_out_b = (const float*)d_in[46];
    const float* ie_w1 = (const float*)d_in[47];
    const float* ie_b1 = (const float*)d_in[48];
    const float* ie_w2 = (const float*)d_in[49];
    const float* ie_b2 = (const float*)d_in[50];
    const float* fin_w = (const float*)d_in[51];
    const float* fin_b = (const float*)d_in[52];
    float* out = (float*)d_out;

    // ---- workspace layout (bump allocator, 256B aligned) ----
    char* pws = (char*)d_ws;
    auto alloc = [&](size_t bytes) -> void* {
        void* r = (void*)pws;
        pws += (bytes + 255) & ~(size_t)255;
        return r;
    };
    short* wsaqkv = (short*)alloc((size_t)LL * 768 * 256 * 2);
    short* wsaout = (short*)alloc((size_t)LL * 256 * 256 * 2);
    short* wcaqkv = (short*)alloc((size_t)LL * 768 * 256 * 2);
    short* wcaout = (short*)alloc((size_t)LL * 256 * 256 * 2);
    short* wffn1  = (short*)alloc((size_t)LL * 1024 * 256 * 2);
    short* wffn2  = (short*)alloc((size_t)LL * 256 * 1024 * 2);
    short* wbe    = (short*)alloc((size_t)256 * 256 * 2);
    short* wtp    = (short*)alloc((size_t)256 * 768 * 2);
    short* wctqkv = (short*)alloc((size_t)768 * 256 * 2);
    short* wctout = (short*)alloc((size_t)256 * 256 * 2);
    short* wce1   = (short*)alloc((size_t)512 * 256 * 2);
    short* wce2   = (short*)alloc((size_t)256 * 512 * 2);
    short* wip    = (short*)alloc((size_t)256 * 512 * 2);
    short* wimqkv = (short*)alloc((size_t)768 * 256 * 2);
    short* wimout = (short*)alloc((size_t)256 * 256 * 2);
    short* wie1   = (short*)alloc((size_t)512 * 256 * 2);
    short* wie2   = (short*)alloc((size_t)256 * 512 * 2);
    short* wfin   = (short*)alloc((size_t)VV * 256 * 2);

    float* xbuf   = (float*)alloc((size_t)MROWS * 256 * 4);
    float* qkvbuf = (float*)alloc((size_t)MROWS * 768 * 4);
    float* qbuf   = (float*)alloc((size_t)MROWS * 256 * 4);
    float* kvbuf  = (float*)alloc((size_t)MROWS * 512 * 4);
    float* ctxbuf = (float*)alloc((size_t)MROWS * 256 * 4);
    float* obuf   = (float*)alloc((size_t)MROWS * 256 * 4);
    float* pbuf   = (float*)alloc((size_t)MROWS * 1024 * 4);
    float* thbuf  = (float*)alloc((size_t)MROWS * 256 * 4);
    float* gatebuf= (float*)alloc((size_t)MROWS * 4 * 4);
    float* ebeh   = (float*)alloc((size_t)MROWS * 256 * 4);
    float* etxt   = (float*)alloc((size_t)MROWS * 256 * 4);
    float* eimg   = (float*)alloc((size_t)MROWS * 256 * 4);
    float* hfin   = (float*)alloc((size_t)MROWS * 256 * 4);

    auto tr = [&](const float* in, short* o, int K, int N) {
        dim3 g((N + 31) / 32, (K + 31) / 32);
        k_transpose_bf16<<<g, dim3(32, 8), 0, stream>>>(in, o, K, N);
    };
    auto gemm = [&](const float* A, int lda, const int* aidx, const short* Bt,
                    const float* bias, float* C, int ldc, int M, int N, int K, int relu) {
        dim3 g((N + 127) / 128, (M + 127) / 128);
        k_gemm_bf16<<<g, 256, 0, stream>>>(A, lda, aidx, Bt, bias, C, ldc, M, N, K, relu);
    };
    auto attn = [&](int mode, const float* q, int qld, const float* k, const float* v,
                    int kvld, const int* mk, float* o, int Tk) {
        dim3 g(1, HH, BB);
        if (mode == 0)      k_attn<0><<<g, 256, 0, stream>>>(q, qld, k, v, kvld, mk, o, TT, Tk);
        else if (mode == 1) k_attn<1><<<g, 256, 0, stream>>>(q, qld, k, v, kvld, mk, o, TT, Tk);
        else                k_attn<2><<<g, 256, 0, stream>>>(q, qld, k, v, kvld, mk, o, TT, Tk);
    };
    auto ln = [&](const float* a, const float* b, const float* gain, const float* beta, float* o) {
        k_ln_res<<<MROWS, 256, 0, stream>>>(a, b, gain, beta, o);
    };

    // ---- weight prep (every call; idempotent, graph-safe) ----
    for (int l = 0; l < LL; ++l) {
        tr(sa_qkv_w + (size_t)l * 256 * 768, wsaqkv + (size_t)l * 768 * 256, 256, 768);
        tr(sa_out_w + (size_t)l * 256 * 256, wsaout + (size_t)l * 256 * 256, 256, 256);
        tr(ca_qkv_w + (size_t)l * 256 * 768, wcaqkv + (size_t)l * 768 * 256, 256, 768);
        tr(ca_out_w + (size_t)l * 256 * 256, wcaout + (size_t)l * 256 * 256, 256, 256);
        tr(ffn_w1 + (size_t)l * 256 * 1024, wffn1 + (size_t)l * 1024 * 256, 256, 1024);
        tr(ffn_w2 + (size_t)l * 1024 * 256, wffn2 + (size_t)l * 256 * 1024, 1024, 256);
    }
    tr(be_w, wbe, 256, 256);
    tr(tp_w, wtp, 768, 256);
    tr(ct_qkv_w, wctqkv, 256, 768);
    tr(ct_out_w, wctout, 256, 256);
    tr(ce_w1, wce1, 256, 512);
    tr(ce_w2, wce2, 512, 256);
    tr(ip_w, wip, 512, 256);
    tr(im_qkv_w, wimqkv, 256, 768);
    tr(im_out_w, wimout, 256, 256);
    tr(ie_w1, wie1, 256, 512);
    tr(ie_w2, wie2, 512, 256);
    tr(fin_w, wfin, 256, VV);

    // ---- embedding ----
    k_embed<<<(MROWS * EE + 255) / 256, 256, 0, stream>>>(ids, item_emb, pos_emb, xbuf);

    // ---- decoder layers ----
    for (int l = 0; l < LL; ++l) {
        // self-attention
        gemm(xbuf, 256, nullptr, wsaqkv + (size_t)l * 768 * 256, sa_qkv_b + (size_t)l * 768,
             qkvbuf, 768, MROWS, 768, 256, 0);
        attn(1, qkvbuf, 768, qkvbuf + 256, qkvbuf + 512, 768, nullptr, ctxbuf, TT);
        gemm(ctxbuf, 256, nullptr, wsaout + (size_t)l * 256 * 256, sa_out_b + (size_t)l * 256,
             obuf, 256, MROWS, 256, 256, 0);
        ln(xbuf, obuf, n1_s + (size_t)l * 256, n1_b + (size_t)l * 256, xbuf);
        // cross-attention (encoder memory)
        gemm(xbuf, 256, nullptr, wcaqkv + (size_t)l * 768 * 256, ca_qkv_b + (size_t)l * 768,
             qbuf, 256, MROWS, 256, 256, 0);
        gemm(enc, 256, nullptr, wcaqkv + (size_t)l * 768 * 256 + 256 * 256,
             ca_qkv_b + (size_t)l * 768 + 256, kvbuf, 512, MENC, 512, 256, 0);
        attn(2, qbuf, 256, kvbuf, kvbuf + 256, 512, mask, ctxbuf, SS);
        gemm(ctxbuf, 256, nullptr, wcaout + (size_t)l * 256 * 256, ca_out_b + (size_t)l * 256,
             obuf, 256, MROWS, 256, 256, 0);
        ln(xbuf, obuf, n2_s + (size_t)l * 256, n2_b + (size_t)l * 256, xbuf);
        // FFN
        gemm(xbuf, 256, nullptr, wffn1 + (size_t)l * 1024 * 256, ffn_b1 + (size_t)l * 1024,
             pbuf, 1024, MROWS, 1024, 256, 1);
        gemm(pbuf, 1024, nullptr, wffn2 + (size_t)l * 256 * 1024, ffn_b2 + (size_t)l * 256,
             obuf, 256, MROWS, 256, 1024, 0);
        ln(xbuf, obuf, n3_s + (size_t)l * 256, n3_b + (size_t)l * 256, xbuf);
    }

    // ---- gate + behavior expert ----
    k_gate<<<MROWS, 64, 0, stream>>>(xbuf, g_w1, g_b1, g_w2, g_b2, gatebuf);
    gemm(xbuf, 256, nullptr, wbe, be_b, ebeh, 256, MROWS, 256, 256, 0);

    // ---- text expert ----
    gemm(text_mat, DTXT, ids, wtp, tp_b, thbuf, 256, MROWS, 256, DTXT, 0);
    gemm(xbuf, 256, nullptr, wctqkv, ct_qkv_b, qbuf, 256, MROWS, 256, 256, 0);
    gemm(thbuf, 256, nullptr, wctqkv + 256 * 256, ct_qkv_b + 256, kvbuf, 512, MROWS, 512, 256, 0);
    attn(0, qbuf, 256, kvbuf, kvbuf + 256, 512, nullptr, ctxbuf, TT);
    gemm(ctxbuf, 256, nullptr, wctout, ct_out_b, obuf, 256, MROWS, 256, 256, 0);
    gemm(obuf, 256, nullptr, wce1, ce_b1, pbuf, 512, MROWS, 512, 256, 1);
    gemm(pbuf, 512, nullptr, wce2, ce_b2, etxt, 256, MROWS, 256, 512, 0);

    // ---- image expert ----
    gemm(img_mat, DIMG, ids, wip, ip_b, thbuf, 256, MROWS, 256, DIMG, 0);
    gemm(xbuf, 256, nullptr, wimqkv, im_qkv_b, qbuf, 256, MROWS, 256, 256, 0);
    gemm(thbuf, 256, nullptr, wimqkv + 256 * 256, im_qkv_b + 256, kvbuf, 512, MROWS, 512, 256, 0);
    attn(0, qbuf, 256, kvbuf, kvbuf + 256, 512, nullptr, ctxbuf, TT);
    gemm(ctxbuf, 256, nullptr, wimout, im_out_b, obuf, 256, MROWS, 256, 256, 0);
    gemm(obuf, 256, nullptr, wie1, ie_b1, pbuf, 512, MROWS, 512, 256, 1);
    gemm(pbuf, 512, nullptr, wie2, ie_b2, eimg, 256, MROWS, 256, 512, 0);

    // ---- combine + final vocab projection ----
    k_combine<<<(MROWS * EE + 255) / 256, 256, 0, stream>>>(gatebuf, ebeh, etxt, eimg, hfin);
    gemm(hfin, 256, nullptr, wfin, fin_b, out, VV, MROWS, VV, 256, 0);
}